// Round 2
// baseline (485.459 us; speedup 1.0000x reference)
//
#include <hip/hip_runtime.h>
#include <math.h>

#define B 8
#define S 2048
#define D 1024
#define NB 256  // grid = 1 block per CU: co-residency unconditionally satisfiable

// ---------------- reduction helpers (256-thread blocks) ----------------
__device__ __forceinline__ float waveReduceSum(float v) {
#pragma unroll
    for (int k = 32; k >= 1; k >>= 1) v += __shfl_xor(v, k, 64);
    return v;
}
__device__ __forceinline__ float waveReduceMax(float v) {
#pragma unroll
    for (int k = 32; k >= 1; k >>= 1) v = fmaxf(v, __shfl_xor(v, k, 64));
    return v;
}
__device__ float blockReduceSum(float v) {
    __shared__ float sm[4];
    int lane = threadIdx.x & 63, wid = threadIdx.x >> 6;
    v = waveReduceSum(v);
    __syncthreads();
    if (lane == 0) sm[wid] = v;
    __syncthreads();
    return sm[0] + sm[1] + sm[2] + sm[3];
}

// ---------------- manual grid barrier (device-scope atomics + fences) --------
// One-shot per launch per slot: arrive-counter + release-flag, both zeroed by
// k_init at the head of each launch (workspace is re-poisoned per iteration).
__device__ __forceinline__ void gbar(unsigned* cnt, unsigned* flag) {
    __threadfence();      // release: make this block's writes device-visible
    __syncthreads();
    if (threadIdx.x == 0) {
        unsigned a = atomicAdd(cnt, 1u);
        if (a == NB - 1u) {
            __threadfence();
            __hip_atomic_store(flag, 1u, __ATOMIC_RELEASE,
                               __HIP_MEMORY_SCOPE_AGENT);
        } else {
            long spins = 0;
            while (__hip_atomic_load(flag, __ATOMIC_ACQUIRE,
                                     __HIP_MEMORY_SCOPE_AGENT) == 0u) {
                __builtin_amdgcn_s_sleep(1);
                if (++spins > (1L << 24)) break;  // failsafe: wrong, not hung
            }
        }
    }
    __syncthreads();
    __threadfence();      // acquire: invalidate stale cached lines
}

// ---------------- shared-memory phase structs ----------------
struct P3S { float part[16][256]; float s_sc[16]; };
struct P4S { float pm[8][128]; float pl[8][128]; float sc[8][128];
             float sM[8]; float sL[8]; float vs[8][32]; };
struct P5S { float sMu[8]; float sInv[8]; float vs[8][32]; };
union ShU { float xs[8192]; P3S p3; P4S p4; P5S p5; };  // 32 KB

// ================= phase bodies (verbatim math, absmax 0.0 lineage) ==========

// P1: q0 = x0 @ Wq + bq. vb in [0,64).
__device__ __forceinline__ void body_q0(int vb, int tid,
        const float* __restrict__ x, const float* __restrict__ Wq,
        const float* __restrict__ bq, float* __restrict__ q0,
        float* shbuf) {
    const int dp0 = vb * 16;
    const int dpl = tid & 15, kg = tid >> 4;
    float (*xs)[1024] = (float(*)[1024])shbuf;
    for (int j = tid; j < 2048; j += 256) {  // 2048 float4 = 8 rows x 256
        int b = j >> 8, off = j & 255;
        ((float4*)xs[b])[off] = ((const float4*)(x + (size_t)b * S * D))[off];
    }
    __syncthreads();
    float acc[8] = {0.f, 0.f, 0.f, 0.f, 0.f, 0.f, 0.f, 0.f};
    const int k0 = kg * 64;
    for (int i = 0; i < 64; ++i) {
        int k = k0 + i;
        float wv = Wq[(size_t)k * D + dp0 + dpl];
#pragma unroll
        for (int b = 0; b < 8; ++b) acc[b] += xs[b][k] * wv;
    }
    __syncthreads();             // all xs reads done before aliasing as red
    float* red = shbuf;          // 2304 floats <= 8192
#pragma unroll
    for (int b = 0; b < 8; ++b) red[(kg * 16 + dpl) * 9 + b] = acc[b];
    __syncthreads();
    if (tid < 128) {
        int dpl2 = tid >> 3, b = tid & 7;
        float s = 0.f;
#pragma unroll
        for (int g = 0; g < 16; ++g) s += red[(g * 16 + dpl2) * 9 + b];
        q0[b * D + dp0 + dpl2] = s + bq[dp0 + dpl2];
    }
    __syncthreads();
}

// P2: u[b,row] = Wk[row,:] . q0[b,:]. vb in [0,256) (4 rows/block).
__device__ __forceinline__ void body_u(int vb, int tid,
        const float* __restrict__ Wk, const float* __restrict__ q0,
        float* __restrict__ u) {
    int wid = (vb * 256 + tid) >> 6;  // row 0..1023
    int lane = tid & 63;
    const float4* Wk4 = (const float4*)(Wk + (size_t)wid * D);
    const float4* q04 = (const float4*)q0;
    float acc[8] = {0.f, 0.f, 0.f, 0.f, 0.f, 0.f, 0.f, 0.f};
#pragma unroll
    for (int i = 0; i < 4; ++i) {
        float4 wv = Wk4[lane + 64 * i];
#pragma unroll
        for (int b = 0; b < 8; ++b) {
            float4 qv = q04[b * 256 + lane + 64 * i];
            acc[b] += wv.x * qv.x + wv.y * qv.y + wv.z * qv.z + wv.w * qv.w;
        }
    }
#pragma unroll
    for (int b = 0; b < 8; ++b) {
        float v = waveReduceSum(acc[b]);
        if (lane == 0) u[b * D + wid] = v;
    }
}

// P3: fused scores + online-softmax partials. vb in [0,1024).
__device__ __forceinline__ void body_attn(int vb, int tid,
        const float* __restrict__ x, const float* __restrict__ u,
        float* __restrict__ pml, float* __restrict__ pw, P3S* p3) {
    const int b = vb >> 7;
    const int bx = vb & 127;
    const int t0 = bx * 16;
    const int wave = tid >> 6, lane = tid & 63;
    const float4* xb4 = (const float4*)(x + (size_t)b * S * D);
    float4 xr[16];
#pragma unroll
    for (int t = 0; t < 16; ++t) xr[t] = xb4[(size_t)(t0 + t) * 256 + tid];
    float4 uv = ((const float4*)(u + b * D))[tid];
#pragma unroll
    for (int t = 0; t < 16; ++t)
        p3->part[t][tid] = xr[t].x * uv.x + xr[t].y * uv.y + xr[t].z * uv.z + xr[t].w * uv.w;
    __syncthreads();
#pragma unroll
    for (int r = 0; r < 4; ++r) {
        int t = wave * 4 + r;
        float v = p3->part[t][lane] + p3->part[t][lane + 64] +
                  p3->part[t][lane + 128] + p3->part[t][lane + 192];
        v = waveReduceSum(v);
        if (lane == 0) p3->s_sc[t] = v * 0.03125f;  // 1/sqrt(1024)
    }
    __syncthreads();
    float m = -INFINITY;
#pragma unroll
    for (int t = 0; t < 16; ++t) m = fmaxf(m, p3->s_sc[t]);
    float l = 0.f;
    float4 wl = {0.f, 0.f, 0.f, 0.f};
#pragma unroll
    for (int t = 0; t < 16; ++t) {
        float p = __expf(p3->s_sc[t] - m);
        l += p;
        wl.x += p * xr[t].x;
        wl.y += p * xr[t].y;
        wl.z += p * xr[t].z;
        wl.w += p * xr[t].w;
    }
    const int pidx = b * 128 + bx;
    ((float4*)(pw + (size_t)pidx * 1024))[tid] = wl;
    if (tid == 0) {
        pml[pidx * 2 + 0] = m;
        pml[pidx * 2 + 1] = l;
    }
    __syncthreads();
}

// P4: combine partials + vecmat Wv -> wacc (atomics). vb in [0,128).
__device__ __forceinline__ void body_comb_wv(int vb, int tid,
        const float* __restrict__ pml, const float* __restrict__ pw,
        const float* __restrict__ Wv, float* __restrict__ wacc, P4S* p4) {
    const int d0 = (vb >> 2) * 32;
    const int dp = (vb & 3) * 256 + tid;
    const int wave = tid >> 6, lane = tid & 63;
    for (int j = tid; j < 1024; j += 256) {
        int b = j >> 7, blk = j & 127;
        p4->pm[b][blk] = pml[(b * 128 + blk) * 2 + 0];
        p4->pl[b][blk] = pml[(b * 128 + blk) * 2 + 1];
    }
    __syncthreads();
#pragma unroll
    for (int h = 0; h < 2; ++h) {
        int b = wave + h * 4;
        float mv = fmaxf(p4->pm[b][lane], p4->pm[b][lane + 64]);
        float M = waveReduceMax(mv);
        float lp = __expf(p4->pm[b][lane] - M) * p4->pl[b][lane] +
                   __expf(p4->pm[b][lane + 64] - M) * p4->pl[b][lane + 64];
        float L = waveReduceSum(lp);
        if (lane == 0) {
            p4->sM[b] = M;
            p4->sL[b] = L;
        }
    }
    __syncthreads();
    for (int j = tid; j < 1024; j += 256) {
        int b = j >> 7, blk = j & 127;
        p4->sc[b][blk] = __expf(p4->pm[b][blk] - p4->sM[b]);
    }
    __syncthreads();
    {
        int b = tid >> 5, dd = tid & 31, d = d0 + dd;
        float acc = 0.f;
#pragma unroll 4
        for (int blk = 0; blk < 128; ++blk)
            acc += p4->sc[b][blk] * pw[(size_t)(b * 128 + blk) * 1024 + d];
        p4->vs[b][dd] = acc / p4->sL[b];
    }
    __syncthreads();
    float acc[8] = {0.f, 0.f, 0.f, 0.f, 0.f, 0.f, 0.f, 0.f};
#pragma unroll 4
    for (int dd = 0; dd < 32; ++dd) {
        float wv = Wv[(size_t)(d0 + dd) * D + dp];
#pragma unroll
        for (int b = 0; b < 8; ++b) acc[b] += p4->vs[b][dd] * wv;
    }
#pragma unroll
    for (int b = 0; b < 8; ++b) atomicAdd(&wacc[b * D + dp], acc[b]);
    __syncthreads();
}

// P5: LN1 stats + vecmat Wd -> hacc (atomics). vb in [0,128).
__device__ __forceinline__ void body_ln1_wd(int vb, int tid,
        const float* __restrict__ wacc, const float* __restrict__ bv,
        const float* __restrict__ x, const float* __restrict__ g1,
        const float* __restrict__ b1, const float* __restrict__ Wd,
        float* __restrict__ hacc, P5S* p5) {
    const int d0 = (vb >> 2) * 32;
    const int dp = (vb & 3) * 256 + tid;
    const int wave = tid >> 6, lane = tid & 63;
    {
        const float4* wacc4 = (const float4*)wacc;
        const float4* bv4 = (const float4*)bv;
#pragma unroll
        for (int h = 0; h < 2; ++h) {
            int b = wave + h * 4;
            const float4* xb4r = (const float4*)(x + (size_t)b * S * D);
            float s = 0.f, ss = 0.f;
#pragma unroll
            for (int i = 0; i < 4; ++i) {
                int idx = lane + 64 * i;
                float4 wv = wacc4[b * 256 + idx];
                float4 bb = bv4[idx];
                float4 xv = xb4r[idx];
                float v0 = wv.x + bb.x + xv.x;
                float v1 = wv.y + bb.y + xv.y;
                float v2 = wv.z + bb.z + xv.z;
                float v3 = wv.w + bb.w + xv.w;
                s += v0 + v1 + v2 + v3;
                ss += v0 * v0 + v1 * v1 + v2 * v2 + v3 * v3;
            }
            s = waveReduceSum(s);
            ss = waveReduceSum(ss);
            if (lane == 0) {
                float mu = s * (1.0f / D);
                p5->sMu[b] = mu;
                p5->sInv[b] = rsqrtf(ss * (1.0f / D) - mu * mu + 1e-5f);
            }
        }
    }
    __syncthreads();
    {
        int b = tid >> 5, dd = tid & 31, d = d0 + dd;
        float v = wacc[b * D + d] + bv[d] + x[(size_t)b * S * D + d];
        p5->vs[b][dd] = (v - p5->sMu[b]) * p5->sInv[b] * g1[d] + b1[d];
    }
    __syncthreads();
    float acc[8] = {0.f, 0.f, 0.f, 0.f, 0.f, 0.f, 0.f, 0.f};
#pragma unroll 4
    for (int dd = 0; dd < 32; ++dd) {
        float wv = Wd[(size_t)(d0 + dd) * D + dp];
#pragma unroll
        for (int b = 0; b < 8; ++b) acc[b] += p5->vs[b][dd] * wv;
    }
#pragma unroll
    for (int b = 0; b < 8; ++b) atomicAdd(&hacc[b * D + dp], acc[b]);
    __syncthreads();
}

// P6: recompute ln1 + ReLU + LN2 + classifier. b in [0,8).
__device__ __forceinline__ void body_final(int b, int tid,
        const float* __restrict__ wacc, const float* __restrict__ bv,
        const float* __restrict__ x, const float* __restrict__ g1,
        const float* __restrict__ b1, const float* __restrict__ hacc,
        const float* __restrict__ bd, const float* __restrict__ g2,
        const float* __restrict__ b2, const float* __restrict__ Wc,
        const float* __restrict__ bc, float* __restrict__ out) {
    float r[4];
    float s = 0.f, ss = 0.f;
#pragma unroll
    for (int i = 0; i < 4; ++i) {
        int e = tid * 4 + i;
        float v = wacc[b * D + e] + bv[e] + x[(size_t)b * S * D + e];
        r[i] = v;
        s += v;
        ss += v * v;
    }
    s = blockReduceSum(s);
    ss = blockReduceSum(ss);
    float mu1 = s * (1.0f / D);
    float inv1 = rsqrtf(ss * (1.0f / D) - mu1 * mu1 + 1e-5f);
    float t[4];
    float s2 = 0.f, ss2 = 0.f;
#pragma unroll
    for (int i = 0; i < 4; ++i) {
        int e = tid * 4 + i;
        float ln1v = (r[i] - mu1) * inv1 * g1[e] + b1[e];
        float h = fmaxf(hacc[b * D + e] + bd[e], 0.f) + ln1v;
        t[i] = h;
        s2 += h;
        ss2 += h * h;
    }
    s2 = blockReduceSum(s2);
    ss2 = blockReduceSum(ss2);
    float mu2 = s2 * (1.0f / D);
    float inv2 = rsqrtf(ss2 * (1.0f / D) - mu2 * mu2 + 1e-5f);
    float p0 = 0.f, p1 = 0.f;
#pragma unroll
    for (int i = 0; i < 4; ++i) {
        int e = tid * 4 + i;
        float l2 = (t[i] - mu2) * inv2 * g2[e] + b2[e];
        p0 += l2 * Wc[e * 2 + 0];
        p1 += l2 * Wc[e * 2 + 1];
    }
    p0 = blockReduceSum(p0);
    p1 = blockReduceSum(p1);
    if (tid == 0) {
        out[b * 2 + 0] = p0 + bc[0];
        out[b * 2 + 1] = p1 + bc[1];
    }
    __syncthreads();
}

// ---------------- workspace layout (floats) ----------------
// q0:0  u:8192  wacc:16384  hacc:24576  pml:32768  pw:34816 (+1048576)
// barrier words (unsigned): float offset 1083392, 10 words [5 x (cnt,flag)]
#define BAR_OFF 1083392

// init: zero the barrier words each launch (ws is re-poisoned per iteration)
__global__ void k_init(unsigned* bars) {
    if (threadIdx.x < 16) bars[threadIdx.x] = 0u;
}

// ================= fused single-dispatch kernel ==============================
__global__ void __launch_bounds__(256) fused_all(
        const float* __restrict__ x,
        const float* __restrict__ Wq, const float* __restrict__ bq,
        const float* __restrict__ Wk,
        const float* __restrict__ Wv, const float* __restrict__ bv,
        const float* __restrict__ Wd, const float* __restrict__ bd,
        const float* __restrict__ g1, const float* __restrict__ b1,
        const float* __restrict__ g2, const float* __restrict__ b2,
        const float* __restrict__ Wc, const float* __restrict__ bc,
        float* __restrict__ out, float* __restrict__ ws) {
    float* q0   = ws;
    float* u    = ws + 8192;
    float* wacc = ws + 16384;
    float* hacc = ws + 24576;
    float* pml  = ws + 32768;
    float* pw   = ws + 34816;
    unsigned* bars = (unsigned*)(ws + BAR_OFF);

    const int tid = threadIdx.x;
    __shared__ ShU sh;

    // zero wacc+hacc (16384 floats) — consumed by P4/P5 atomics (3 bars away)
    for (int i = blockIdx.x * 256 + tid; i < 16384; i += NB * 256) wacc[i] = 0.f;

    for (int vb = blockIdx.x; vb < 64; vb += NB)
        body_q0(vb, tid, x, Wq, bq, q0, sh.xs);
    gbar(&bars[0], &bars[1]);
    for (int vb = blockIdx.x; vb < 256; vb += NB)
        body_u(vb, tid, Wk, q0, u);
    gbar(&bars[2], &bars[3]);
    for (int vb = blockIdx.x; vb < 1024; vb += NB)
        body_attn(vb, tid, x, u, pml, pw, &sh.p3);
    gbar(&bars[4], &bars[5]);
    for (int vb = blockIdx.x; vb < 128; vb += NB)
        body_comb_wv(vb, tid, pml, pw, Wv, wacc, &sh.p4);
    gbar(&bars[6], &bars[7]);
    for (int vb = blockIdx.x; vb < 128; vb += NB)
        body_ln1_wd(vb, tid, wacc, bv, x, g1, b1, Wd, hacc, &sh.p5);
    gbar(&bars[8], &bars[9]);
    for (int vb = blockIdx.x; vb < 8; vb += NB)
        body_final(vb, tid, wacc, bv, x, g1, b1, hacc, bd, g2, b2, Wc, bc, out);
}

extern "C" void kernel_launch(void* const* d_in, const int* in_sizes, int n_in,
                              void* d_out, int out_size, void* d_ws, size_t ws_size,
                              hipStream_t stream) {
    const float* x  = (const float*)d_in[0];
    const float* Wq = (const float*)d_in[1];
    const float* bq = (const float*)d_in[2];
    const float* Wk = (const float*)d_in[3];
    // bk (d_in[4]): constant over t -> cancels in softmax
    const float* Wv = (const float*)d_in[5];
    const float* bv = (const float*)d_in[6];
    const float* Wd = (const float*)d_in[7];
    const float* bd = (const float*)d_in[8];
    const float* g1 = (const float*)d_in[9];
    const float* b1 = (const float*)d_in[10];
    const float* g2 = (const float*)d_in[11];
    const float* b2 = (const float*)d_in[12];
    const float* Wc = (const float*)d_in[13];
    const float* bc = (const float*)d_in[14];
    float* out = (float*)d_out;
    float* ws = (float*)d_ws;

    k_init<<<1, 64, 0, stream>>>((unsigned*)(ws + BAR_OFF));
    fused_all<<<NB, 256, 0, stream>>>(x, Wq, bq, Wk, Wv, bv, Wd, bd,
                                      g1, b1, g2, b2, Wc, bc, out, ws);
}

// Round 4
// 155.993 us; speedup vs baseline: 3.1121x; 3.1121x over previous
//
#include <hip/hip_runtime.h>
#include <math.h>

#define B 8
#define S 2048
#define D 1024

// ---------------- reduction helpers (256-thread blocks) ----------------
__device__ __forceinline__ float waveReduceSum(float v) {
#pragma unroll
    for (int k = 32; k >= 1; k >>= 1) v += __shfl_xor(v, k, 64);
    return v;
}
__device__ __forceinline__ float waveReduceMax(float v) {
#pragma unroll
    for (int k = 32; k >= 1; k >>= 1) v = fmaxf(v, __shfl_xor(v, k, 64));
    return v;
}
__device__ float blockReduceSum(float v) {
    __shared__ float sm[4];
    int lane = threadIdx.x & 63, wid = threadIdx.x >> 6;
    v = waveReduceSum(v);
    __syncthreads();
    if (lane == 0) sm[wid] = v;
    __syncthreads();
    return sm[0] + sm[1] + sm[2] + sm[3];
}

// ---------------- K1: q0 = x0 @ Wq + bq (independent float4 loads) -----------
// grid 64, block 256. Block owns a 16-wide dp chunk (4 float4 columns).
// Threads: dpf = tid&3 (float4 column), kg = tid>>2 (64 k-groups of 16).
// Each thread: 16 INDEPENDENT float4 Wq loads (vs 64 serial scalar loads
// before) -> latency pipelined. 3-stage LDS tree reduction.
// Also zeroes the wacc+hacc accumulator region (16384 floats, 256/block).
__global__ void __launch_bounds__(256) k1_q0(const float* __restrict__ x,
                                             const float* __restrict__ Wq,
                                             const float* __restrict__ bq,
                                             float* __restrict__ q0,
                                             float* __restrict__ zero_region) {
    const int tid = threadIdx.x;
    zero_region[blockIdx.x * 256 + tid] = 0.f;  // 64*256 == 16384 exactly

    const int dp0 = blockIdx.x * 16;
    const int dpf = tid & 3;   // float4 column within the 16-wide chunk
    const int kg = tid >> 2;   // 64 k-groups of 16
    __shared__ float xs[8][1024];        // 32 KB (aliased as redA after use)
    __shared__ float4 redB[8 * 4 * 8];   // 4 KB (kh, dpf, b)
    for (int j = tid; j < 2048; j += 256) {  // 2048 float4 = 8 rows x 256
        int b = j >> 8, off = j & 255;
        ((float4*)xs[b])[off] = ((const float4*)(x + (size_t)b * S * D))[off];
    }
    __syncthreads();
    const float4* Wq4 = (const float4*)Wq + (dp0 >> 2) + dpf;  // row stride 256
    float4 acc4[8];
#pragma unroll
    for (int b = 0; b < 8; ++b) acc4[b] = make_float4(0.f, 0.f, 0.f, 0.f);
    const int k0 = kg * 16;
#pragma unroll
    for (int i = 0; i < 16; ++i) {
        int k = k0 + i;
        float4 w4 = Wq4[(size_t)k * 256];
#pragma unroll
        for (int b = 0; b < 8; ++b) {
            float xv = xs[b][k];
            acc4[b].x += xv * w4.x;
            acc4[b].y += xv * w4.y;
            acc4[b].z += xv * w4.z;
            acc4[b].w += xv * w4.w;
        }
    }
    __syncthreads();             // all xs reads done before aliasing as redA
    float4* redA = (float4*)xs;  // 2048 float4 = 32 KB, exact fit
#pragma unroll
    for (int b = 0; b < 8; ++b) redA[(kg * 4 + dpf) * 8 + b] = acc4[b];
    __syncthreads();
    {   // stage A: 256 threads, each sums 8 kg-partials
        int b = tid & 7, dpf2 = (tid >> 3) & 3, kh = tid >> 5;
        float4 s = make_float4(0.f, 0.f, 0.f, 0.f);
#pragma unroll
        for (int g = 0; g < 8; ++g) {
            float4 v = redA[((kh * 8 + g) * 4 + dpf2) * 8 + b];
            s.x += v.x; s.y += v.y; s.z += v.z; s.w += v.w;
        }
        redB[(kh * 4 + dpf2) * 8 + b] = s;
    }
    __syncthreads();
    if (tid < 32) {  // stage B: 32 outputs (8 b x 4 float4 columns)
        int b = tid & 7, dpf2 = tid >> 3;
        float4 s = make_float4(0.f, 0.f, 0.f, 0.f);
#pragma unroll
        for (int g = 0; g < 8; ++g) {
            float4 v = redB[(g * 4 + dpf2) * 8 + b];
            s.x += v.x; s.y += v.y; s.z += v.z; s.w += v.w;
        }
        const float4 bb = ((const float4*)bq)[(dp0 >> 2) + dpf2];
        float4 o;
        o.x = s.x + bb.x; o.y = s.y + bb.y; o.z = s.z + bb.z; o.w = s.w + bb.w;
        ((float4*)(q0 + (size_t)b * D + dp0))[dpf2] = o;
    }
}

// ---------------- K2: u[b,row] = Wk[row,:] . q0[b,:] (one wave per row) ------
__global__ void __launch_bounds__(256) k2_u(const float* __restrict__ Wk,
                                            const float* __restrict__ q0,
                                            float* __restrict__ u) {
    int wid = (blockIdx.x * 256 + threadIdx.x) >> 6;  // row 0..1023
    int lane = threadIdx.x & 63;
    const float4* Wk4 = (const float4*)(Wk + (size_t)wid * D);
    const float4* q04 = (const float4*)q0;
    float acc[8] = {0.f, 0.f, 0.f, 0.f, 0.f, 0.f, 0.f, 0.f};
#pragma unroll
    for (int i = 0; i < 4; ++i) {
        float4 wv = Wk4[lane + 64 * i];
#pragma unroll
        for (int b = 0; b < 8; ++b) {
            float4 qv = q04[b * 256 + lane + 64 * i];
            acc[b] += wv.x * qv.x + wv.y * qv.y + wv.z * qv.z + wv.w * qv.w;
        }
    }
#pragma unroll
    for (int b = 0; b < 8; ++b) {
        float v = waveReduceSum(acc[b]);
        if (lane == 0) u[b * D + wid] = v;
    }
}

// ---------------- K3: fused scores + online-softmax partials (x once, in regs)
// grid (128, 8), block 256. Block: 16 t's of batch b.
__global__ void __launch_bounds__(256) k3_attn(const float* __restrict__ x,
                                               const float* __restrict__ u,
                                               float* __restrict__ pml,
                                               float* __restrict__ pw) {
    const int b = blockIdx.y;
    const int t0 = blockIdx.x * 16;
    const int tid = threadIdx.x;
    const int wave = tid >> 6, lane = tid & 63;
    const float4* xb4 = (const float4*)(x + (size_t)b * S * D);
    float4 xr[16];
#pragma unroll
    for (int t = 0; t < 16; ++t) xr[t] = xb4[(size_t)(t0 + t) * 256 + tid];
    float4 uv = ((const float4*)(u + b * D))[tid];
    __shared__ float part[16][256];
#pragma unroll
    for (int t = 0; t < 16; ++t)
        part[t][tid] = xr[t].x * uv.x + xr[t].y * uv.y + xr[t].z * uv.z + xr[t].w * uv.w;
    __syncthreads();
    __shared__ float s_sc[16];
#pragma unroll
    for (int r = 0; r < 4; ++r) {
        int t = wave * 4 + r;
        float v = part[t][lane] + part[t][lane + 64] + part[t][lane + 128] + part[t][lane + 192];
        v = waveReduceSum(v);
        if (lane == 0) s_sc[t] = v * 0.03125f;  // 1/sqrt(1024)
    }
    __syncthreads();
    float m = -INFINITY;
#pragma unroll
    for (int t = 0; t < 16; ++t) m = fmaxf(m, s_sc[t]);
    float p[16], l = 0.f;
#pragma unroll
    for (int t = 0; t < 16; ++t) {
        p[t] = __expf(s_sc[t] - m);
        l += p[t];
    }
    float4 wl = {0.f, 0.f, 0.f, 0.f};
#pragma unroll
    for (int t = 0; t < 16; ++t) {
        wl.x += p[t] * xr[t].x;
        wl.y += p[t] * xr[t].y;
        wl.z += p[t] * xr[t].z;
        wl.w += p[t] * xr[t].w;
    }
    const int pidx = b * 128 + blockIdx.x;
    ((float4*)(pw + (size_t)pidx * 1024))[tid] = wl;
    if (tid == 0) {
        pml[pidx * 2 + 0] = m;
        pml[pidx * 2 + 1] = l;
    }
}

// ---------------- K4: combine partials (local slice) + vecmat Wv -> wacc -----
// grid 128, block 256. K-chunk d0=(bid>>2)*32, dp-chunk (bid&3)*256.
__global__ void __launch_bounds__(256) k4_comb_wv(const float* __restrict__ pml,
                                                  const float* __restrict__ pw,
                                                  const float* __restrict__ Wv,
                                                  float* __restrict__ wacc) {
    const int tid = threadIdx.x;
    const int bid = blockIdx.x;
    const int d0 = (bid >> 2) * 32;
    const int dp = (bid & 3) * 256 + tid;
    const int wave = tid >> 6, lane = tid & 63;
    __shared__ float pm[8][128], pl[8][128], sc[8][128];
    __shared__ float sM[8], sL[8];
    __shared__ float vs[8][32];
    for (int j = tid; j < 1024; j += 256) {
        int b = j >> 7, blk = j & 127;
        pm[b][blk] = pml[(b * 128 + blk) * 2 + 0];
        pl[b][blk] = pml[(b * 128 + blk) * 2 + 1];
    }
    __syncthreads();
    // per-batch M and L: wave w handles batches w and w+4
#pragma unroll
    for (int h = 0; h < 2; ++h) {
        int b = wave + h * 4;
        float mv = fmaxf(pm[b][lane], pm[b][lane + 64]);
        float M = waveReduceMax(mv);
        float lp = __expf(pm[b][lane] - M) * pl[b][lane] +
                   __expf(pm[b][lane + 64] - M) * pl[b][lane + 64];
        float L = waveReduceSum(lp);
        if (lane == 0) {
            sM[b] = M;
            sL[b] = L;
        }
    }
    __syncthreads();
    for (int j = tid; j < 1024; j += 256) {
        int b = j >> 7, blk = j & 127;
        sc[b][blk] = __expf(pm[b][blk] - sM[b]);
    }
    __syncthreads();
    // combine: thread -> (b = tid>>5, dd = tid&31). unroll 16: 8 latency
    // rounds of 16 independent loads instead of 32 rounds of 4.
    {
        int b = tid >> 5, dd = tid & 31, d = d0 + dd;
        float acc = 0.f;
#pragma unroll 16
        for (int blk = 0; blk < 128; ++blk)
            acc += sc[b][blk] * pw[(size_t)(b * 128 + blk) * 1024 + d];
        vs[b][dd] = acc / sL[b];
    }
    __syncthreads();
    float acc[8] = {0.f, 0.f, 0.f, 0.f, 0.f, 0.f, 0.f, 0.f};
#pragma unroll 8
    for (int dd = 0; dd < 32; ++dd) {
        float wv = Wv[(size_t)(d0 + dd) * D + dp];
#pragma unroll
        for (int b = 0; b < 8; ++b) acc[b] += vs[b][dd] * wv;
    }
#pragma unroll
    for (int b = 0; b < 8; ++b) atomicAdd(&wacc[b * D + dp], acc[b]);
}

// ---------------- K5: LN1 (wave-parallel stats) + vecmat Wd -> hacc ----------
// grid 128, block 256.
__global__ void __launch_bounds__(256) k5_ln1_wd(const float* __restrict__ wacc,
                                                 const float* __restrict__ bv,
                                                 const float* __restrict__ x,
                                                 const float* __restrict__ g1,
                                                 const float* __restrict__ b1,
                                                 const float* __restrict__ Wd,
                                                 float* __restrict__ hacc) {
    const int tid = threadIdx.x;
    const int bid = blockIdx.x;
    const int d0 = (bid >> 2) * 32;
    const int dp = (bid & 3) * 256 + tid;
    const int wave = tid >> 6, lane = tid & 63;
    __shared__ float sMu[8], sInv[8], vs[8][32];
    {
        const float4* wacc4 = (const float4*)wacc;
        const float4* bv4 = (const float4*)bv;
#pragma unroll
        for (int h = 0; h < 2; ++h) {
            int b = wave + h * 4;
            const float4* xb4r = (const float4*)(x + (size_t)b * S * D);
            float s = 0.f, ss = 0.f;
#pragma unroll
            for (int i = 0; i < 4; ++i) {
                int idx = lane + 64 * i;
                float4 wv = wacc4[b * 256 + idx];
                float4 bb = bv4[idx];
                float4 xv = xb4r[idx];
                float v0 = wv.x + bb.x + xv.x;
                float v1 = wv.y + bb.y + xv.y;
                float v2 = wv.z + bb.z + xv.z;
                float v3 = wv.w + bb.w + xv.w;
                s += v0 + v1 + v2 + v3;
                ss += v0 * v0 + v1 * v1 + v2 * v2 + v3 * v3;
            }
            s = waveReduceSum(s);
            ss = waveReduceSum(ss);
            if (lane == 0) {
                float mu = s * (1.0f / D);
                sMu[b] = mu;
                sInv[b] = rsqrtf(ss * (1.0f / D) - mu * mu + 1e-5f);
            }
        }
    }
    __syncthreads();
    {
        int b = tid >> 5, dd = tid & 31, d = d0 + dd;
        float v = wacc[b * D + d] + bv[d] + x[(size_t)b * S * D + d];
        vs[b][dd] = (v - sMu[b]) * sInv[b] * g1[d] + b1[d];
    }
    __syncthreads();
    float acc[8] = {0.f, 0.f, 0.f, 0.f, 0.f, 0.f, 0.f, 0.f};
#pragma unroll 8
    for (int dd = 0; dd < 32; ++dd) {
        float wv = Wd[(size_t)(d0 + dd) * D + dp];
#pragma unroll
        for (int b = 0; b < 8; ++b) acc[b] += vs[b][dd] * wv;
    }
#pragma unroll
    for (int b = 0; b < 8; ++b) atomicAdd(&hacc[b * D + dp], acc[b]);
}

// ---------------- K6: recompute ln1 row + ReLU + LN2 + classifier -> out -----
// grid 8, block 256.
__global__ void __launch_bounds__(256) k6_final(const float* __restrict__ wacc,
                                                const float* __restrict__ bv,
                                                const float* __restrict__ x,
                                                const float* __restrict__ g1,
                                                const float* __restrict__ b1,
                                                const float* __restrict__ hacc,
                                                const float* __restrict__ bd,
                                                const float* __restrict__ g2,
                                                const float* __restrict__ b2,
                                                const float* __restrict__ Wc,
                                                const float* __restrict__ bc,
                                                float* __restrict__ out) {
    const int b = blockIdx.x;
    const int tid = threadIdx.x;
    float r[4];
    float s = 0.f, ss = 0.f;
#pragma unroll
    for (int i = 0; i < 4; ++i) {
        int e = tid * 4 + i;
        float v = wacc[b * D + e] + bv[e] + x[(size_t)b * S * D + e];
        r[i] = v;
        s += v;
        ss += v * v;
    }
    s = blockReduceSum(s);
    ss = blockReduceSum(ss);
    float mu1 = s * (1.0f / D);
    float inv1 = rsqrtf(ss * (1.0f / D) - mu1 * mu1 + 1e-5f);
    float t[4];
    float s2 = 0.f, ss2 = 0.f;
#pragma unroll
    for (int i = 0; i < 4; ++i) {
        int e = tid * 4 + i;
        float ln1v = (r[i] - mu1) * inv1 * g1[e] + b1[e];
        float h = fmaxf(hacc[b * D + e] + bd[e], 0.f) + ln1v;
        t[i] = h;
        s2 += h;
        ss2 += h * h;
    }
    s2 = blockReduceSum(s2);
    ss2 = blockReduceSum(ss2);
    float mu2 = s2 * (1.0f / D);
    float inv2 = rsqrtf(ss2 * (1.0f / D) - mu2 * mu2 + 1e-5f);
    float p0 = 0.f, p1 = 0.f;
#pragma unroll
    for (int i = 0; i < 4; ++i) {
        int e = tid * 4 + i;
        float l2 = (t[i] - mu2) * inv2 * g2[e] + b2[e];
        p0 += l2 * Wc[e * 2 + 0];
        p1 += l2 * Wc[e * 2 + 1];
    }
    p0 = blockReduceSum(p0);
    p1 = blockReduceSum(p1);
    if (tid == 0) {
        out[b * 2 + 0] = p0 + bc[0];
        out[b * 2 + 1] = p1 + bc[1];
    }
}

extern "C" void kernel_launch(void* const* d_in, const int* in_sizes, int n_in,
                              void* d_out, int out_size, void* d_ws, size_t ws_size,
                              hipStream_t stream) {
    const float* x  = (const float*)d_in[0];
    const float* Wq = (const float*)d_in[1];
    const float* bq = (const float*)d_in[2];
    const float* Wk = (const float*)d_in[3];
    // bk (d_in[4]): constant over t -> cancels in softmax
    const float* Wv = (const float*)d_in[5];
    const float* bv = (const float*)d_in[6];
    const float* Wd = (const float*)d_in[7];
    const float* bd = (const float*)d_in[8];
    const float* g1 = (const float*)d_in[9];
    const float* b1 = (const float*)d_in[10];
    const float* g2 = (const float*)d_in[11];
    const float* b2 = (const float*)d_in[12];
    const float* Wc = (const float*)d_in[13];
    const float* bc = (const float*)d_in[14];
    float* out = (float*)d_out;

    float* ws   = (float*)d_ws;
    float* q0   = ws;           // [8,1024] written whole by K1
    float* u    = ws + 8192;    // [8,1024]
    float* wacc = ws + 16384;   // [8,1024] zeroed by K1, atomics in K4
    float* hacc = ws + 24576;   // [8,1024] zeroed by K1, atomics in K5
    float* pml  = ws + 32768;   // [8,128,2]
    float* pw   = ws + 34816;   // [8,128,1024] (byte off 139264, 16B-aligned)

    // K1: q0 = x0 @ Wq + bq ; also zeroes wacc+hacc (contiguous 16384 floats)
    k1_q0<<<64, 256, 0, stream>>>(x, Wq, bq, q0, wacc);
    // K2: u = Wk @ q0
    k2_u<<<256, 256, 0, stream>>>(Wk, q0, u);
    // K3: attention partials (single x pass)
    k3_attn<<<dim3(128, 8), 256, 0, stream>>>(x, u, pml, pw);
    // K4: combine + @Wv -> wacc
    k4_comb_wv<<<128, 256, 0, stream>>>(pml, pw, Wv, wacc);
    // K5: LN1 (wave-parallel stats) + @Wd -> hacc
    k5_ln1_wd<<<128, 256, 0, stream>>>(wacc, bv, x, g1, b1, Wd, hacc);
    // K6: ln1 recompute + ReLU + LN2 + classifier
    k6_final<<<8, 256, 0, stream>>>(wacc, bv, x, g1, b1, hacc, bd, g2, b2, Wc, bc, out);
}